// Round 1
// 315.920 us; speedup vs baseline: 1.3607x; 1.3607x over previous
//
#include <hip/hip_runtime.h>
#include <hip/hip_bf16.h>
#include <math.h>

// B_T=32, T=8 -> B=4; N=2048, E=8192, D=128, H=8, dh=16
// Index algebra (HW-verified R1/R2): flat reshape g = s*8 + cg;
//   q:   h = u_in_batch>>11 (= t_idx), s' = node*8+cg, rope pos = node>>8
//   k/v: h = (u&65535)>>13, rope pos = (u&8191)>>10 (block-uniform, 128-row blocks)
// x_0/Wk0/Wv0 branch is DEAD (out overwritten by edge iteration).
// R6: k_kv restructured for occupancy (was 22% -> latency-bound, all pipes idle):
//   - each wave owns MATCHED k/v chunk pair {2w,2w+1} -> kv partial is wave-local
//     (k-chunk c pairs with v-chunk c at the same slot), no cross-wave LDS hand-off
//   - rt processed in pairs (acc 128->32 regs), per-wave 4KB transpose bufs
//   - LDS 64KB->48KB, __launch_bounds__(256,3): 3 blocks/CU, 3 waves/SIMD
//   - barriers 3->1 (wave-local s_waitcnt lgkmcnt(0) replaces cross-wave syncs)
//   - softmax epilogue balanced: every wave 2 chunks (was: waves 0,2 did 4, waves 1,3 idle)
//   - f2bf/pk2 now via v_cvt_pk_bf16_f32 path (RNE, same as old manual rounding)

typedef __attribute__((ext_vector_type(8))) short short8;
typedef __attribute__((ext_vector_type(4))) float float4v;

#define LN1E4_OVER8 1.1512925464970229f

// ws float offsets
#define OFF_QWS   0                    // q' bf16 [b][h][s'][16]: 8388608 shorts = 4194304 floats
#define OFF_FRG_Q 4194304              // Wq B-frags bf16: 16384 shorts = 8192 floats
#define OFF_FRG_O 4202496              // Wo B-frags bf16: 16384 shorts
#define OFF_BFRG  4210688              // Wk|Wv B-frags bf16 (16 chunks): 32768 shorts = 16384 floats
#define OFF_KV    4227072              // [b*8+h][16][16] floats
#define OFF_KCS   4235264              // [b*8+h][16] floats
#define OFF_PART  4235776              // 2048 blocks x 4 waves x 272 floats -> end 6464000 (25.9 MB)

__device__ __forceinline__ unsigned short f2bf(float f) {
    __hip_bfloat16 h = __float2bfloat16(f);          // RNE
    return *reinterpret_cast<unsigned short*>(&h);
}
__device__ __forceinline__ float bf2f(unsigned short s) {
    return __uint_as_float(((unsigned)s) << 16);
}
__device__ __forceinline__ unsigned pk2(float a, float b) {
    __hip_bfloat162 h = __float22bfloat162_rn(make_float2(a, b));   // a -> low 16, b -> high 16
    return *reinterpret_cast<unsigned*>(&h);
}
// DPP helpers (16-lane butterfly within one DPP row) — used only in exonerated k_q/k_out
template<int C> __device__ __forceinline__ float dppadd(float x) {
    int r = __builtin_amdgcn_update_dpp(0, __float_as_int(x), C, 0xF, 0xF, true);
    return x + __int_as_float(r);
}
__device__ __forceinline__ float sum16(float x) {
    x = dppadd<0xB1>(x);    // xor1
    x = dppadd<0x4E>(x);    // xor2
    x = dppadd<0x141>(x);   // row_half_mirror (xor4)
    x = dppadd<0x140>(x);   // row_mirror (xor8)
    return x;
}
__device__ __forceinline__ float qperm1(float x) {  // value from lane n^1
    int r = __builtin_amdgcn_update_dpp(0, __float_as_int(x), 0xB1, 0xF, 0xF, true);
    return __int_as_float(r);
}

// ---------------- prep: Wq / Wo B-frags + R2-style combined Wk|Wv B-frag table ----------------
__global__ void k_prep(const float* __restrict__ Wq, const float* __restrict__ Wk1,
                       const float* __restrict__ Wv1, const float* __restrict__ Wo,
                       float* __restrict__ ws) {
    int i = blockIdx.x * 256 + threadIdx.x;
    if (i < 32768) {                      // Wq / Wo frags: B[k][n] = W[n][k], MFMA lane order
        int j = i & 16383;
        int jE = j & 7, lane = (j >> 3) & 63, km = (j >> 9) & 3, cg = j >> 11;
        int n = cg * 16 + (lane & 15);
        int kk = km * 32 + (lane >> 4) * 8 + jE;
        const float* W = (i < 16384) ? Wq : Wo;
        unsigned short* dst = (unsigned short*)(ws + ((i < 16384) ? OFF_FRG_Q : OFF_FRG_O));
        dst[j] = f2bf(W[n * 128 + kk]);
    } else {                              // R2-verified combined table: cg<8 -> Wk1, else Wv1
        int j = i - 32768;                // 0..32767
        int jE = j & 7, lane = (j >> 3) & 63, km = (j >> 9) & 3, cg = j >> 11;
        int n = cg * 16 + (lane & 15);
        int k = km * 32 + (lane >> 4) * 8 + jE;
        float w = (cg < 8) ? Wk1[n * 128 + k] : Wv1[(n - 128) * 128 + k];
        ((unsigned short*)(ws + OFF_BFRG))[j] = f2bf(w);
    }
}

// ---------------- K1 (R3, exonerated): Q MFMA GEMM + softmax(16) + rope -> bf16 qws ----------------
// 128 rows/block, 512 blocks. wave w owns chunks {2w, 2w+1}.
__global__ __launch_bounds__(256, 2) void k_q(const float* __restrict__ qd,
                                              const float* __restrict__ bq,
                                              float* __restrict__ ws) {
    __shared__ __align__(16) unsigned short aT[128 * 128];
    unsigned* qws32 = (unsigned*)(ws + OFF_QWS);
    int t = threadIdx.x, blk = blockIdx.x;
    int wave = t >> 6, lane = t & 63, quad = lane >> 4, n = lane & 15;
    long base = (long)blk * 128;
    int b = blk >> 7;
    int h = (blk & 127) >> 4;
    int s0 = (blk & 15) * 1024;
    int t1 = (blk & 15) >> 1;           // rope position (block-uniform: 128-row span inside 256-node span)

    const short8* fq = (const short8*)((const unsigned short*)(ws + OFF_FRG_Q));
    short8 Bf[2][4];
    #pragma unroll
    for (int ct = 0; ct < 2; ++ct)
        #pragma unroll
        for (int km = 0; km < 4; ++km)
            Bf[ct][km] = fq[((2 * wave + ct) * 4 + km) * 64 + lane];

    #pragma unroll
    for (int i = 0; i < 16; ++i) {
        int idx = i * 256 + t;
        int row = idx >> 5, c4 = idx & 31;
        float4 v = ((const float4*)qd)[(base + row) * 32 + c4];
        unsigned short* p = aT + row * 128 + (((c4 >> 1) ^ (row & 7)) << 3) + (c4 & 1) * 4;
        *(uint2*)p = make_uint2(pk2(v.x, v.y), pk2(v.z, v.w));
    }
    __syncthreads();

    float4v acc[8][2];
    #pragma unroll
    for (int rt = 0; rt < 8; ++rt)
        #pragma unroll
        for (int ct = 0; ct < 2; ++ct) acc[rt][ct] = (float4v){0.f, 0.f, 0.f, 0.f};

    #pragma unroll
    for (int rt = 0; rt < 8; ++rt) {
        int row = rt * 16 + n;
        #pragma unroll
        for (int km = 0; km < 4; ++km) {
            short8 Af = *(const short8*)(aT + row * 128 + (((km * 4 + quad) ^ (n & 7)) << 3));
            acc[rt][0] = __builtin_amdgcn_mfma_f32_16x16x32_bf16(Af, Bf[0][km], acc[rt][0], 0, 0, 0);
            acc[rt][1] = __builtin_amdgcn_mfma_f32_16x16x32_bf16(Af, Bf[1][km], acc[rt][1], 0, 0, 0);
        }
    }

    float fr = __expf(-LN1E4_OVER8 * (float)(n >> 1));
    float sa, ca; __sincosf((float)t1 * fr, &sa, &ca);
    float sgn = (n & 1) ? sa : -sa;

    #pragma unroll
    for (int rt = 0; rt < 8; ++rt)
        #pragma unroll
        for (int ct = 0; ct < 2; ++ct) {
            int cg = 2 * wave + ct;
            float bias = bq[cg * 16 + n];
            float4v x = acc[rt][ct];
            #pragma unroll
            for (int i = 0; i < 4; ++i) {
                float e = __expf(x[i] + bias);          // logits ~N(0,0.23): exp-safe
                float s = sum16(e);
                float q = e / s;
                float r = fmaf(qperm1(q), sgn, q * ca); // rope post-softmax
                unsigned pkd = ((unsigned)f2bf(qperm1(r)) << 16) | (unsigned)f2bf(r);
                if ((n & 1) == 0) {
                    int sp = s0 + (rt * 16 + quad * 4 + i) * 8 + cg;
                    long qoff = ((long)(b * 8 + h) * 16384 + sp) * 16 + n;  // shorts
                    qws32[qoff >> 1] = pkd;
                }
            }
        }
}

// ---------------- K2 (R6): edge K/V MFMA + rope/softmax + WAVE-LOCAL kv MFMA ----------------
// 128 rows/block, 2048 blocks. wave w owns k-chunks {2w,2w+1} AND v-chunks {2w,2w+1}.
// Matched chunk pairing makes the kv partial wave-local: slot s = c*128+row has
// k from k-chunk c and v from v-chunk c -> no cross-wave LDS, 1 barrier total.
__global__ __launch_bounds__(256, 3) void k_kv(const float* __restrict__ ea,
                                               const float* __restrict__ bk,
                                               const float* __restrict__ bv,
                                               float* __restrict__ ws) {
    __shared__ __align__(16) char smem[49152];              // 32KB aT + 4 x 4KB wave bufs
    unsigned short* aT = (unsigned short*)smem;             // [128][128] bf16 XOR-swizzled

    int t = threadIdx.x, blk = blockIdx.x;
    int wave = t >> 6, lane = t & 63, quad = lane >> 4, n = lane & 15;
    unsigned short* kbuf = (unsigned short*)(smem + 32768) + wave * 2048;  // [16][64] bf16 swizzled
    unsigned short* vbuf = kbuf + 1024;                                    // [16][64]
    long base = (long)blk * 128;
    int sl = (blk & 511) << 7;                    // row within batch
    int t2 = (sl & 8191) >> 10;                   // block-uniform rope timestep

    // stage A tile fp32 -> bf16 LDS (verified swizzle, unchanged)
    #pragma unroll
    for (int i = 0; i < 16; ++i) {
        int idx = i * 256 + t;
        int row = idx >> 5, c4 = idx & 31;
        float4 v = ((const float4*)ea)[(base + row) * 32 + c4];
        unsigned short* p = aT + row * 128 + (((c4 >> 1) ^ (row & 7)) << 3) + (c4 & 1) * 4;
        *(uint2*)p = make_uint2(pk2(v.x, v.y), pk2(v.z, v.w));
    }

    // B fragments: ct0,1 = Wk chunks 2w,2w+1 ; ct2,3 = Wv chunks 2w,2w+1 (table: cg<8 k, cg>=8 v)
    const short8* bfrag = (const short8*)((const unsigned short*)(ws + OFF_BFRG));
    short8 Bf[4][4];
    #pragma unroll
    for (int ct = 0; ct < 4; ++ct) {
        int cg = (ct < 2) ? (2 * wave + ct) : (8 + 2 * wave + (ct - 2));
        #pragma unroll
        for (int km = 0; km < 4; ++km)
            Bf[ct][km] = bfrag[(cg * 4 + km) * 64 + lane];
    }

    float bias[4];
    #pragma unroll
    for (int ct = 0; ct < 4; ++ct)
        bias[ct] = (ct < 2) ? bk[(2 * wave + ct) * 16 + n] : bv[(2 * wave + ct - 2) * 16 + n];
    float fr = __expf(-LN1E4_OVER8 * (float)(n >> 1));
    float sv, cvv; __sincosf((float)t2 * fr, &sv, &cvv);
    float sgn = (n & 1) ? sv : -sv;   // rope: out = x*cos + partner*sgn
    float kcsacc = 0.f;
    float4v kvacc = (float4v){0.f, 0.f, 0.f, 0.f};

    __syncthreads();                  // the ONLY barrier: aT staged, never overwritten

    #pragma unroll
    for (int pair = 0; pair < 4; ++pair) {
        // GEMM rows [pair*32, pair*32+32): acc[2][4] = 32 regs (was 128)
        float4v acc[2][4];
        #pragma unroll
        for (int rtl = 0; rtl < 2; ++rtl)
            #pragma unroll
            for (int ct = 0; ct < 4; ++ct) acc[rtl][ct] = (float4v){0.f, 0.f, 0.f, 0.f};

        #pragma unroll
        for (int rtl = 0; rtl < 2; ++rtl) {
            int row = (pair * 2 + rtl) * 16 + n;
            short8 Af[4];
            #pragma unroll
            for (int km = 0; km < 4; ++km)
                Af[km] = *(const short8*)(aT + row * 128 + (((km * 4 + quad) ^ (n & 7)) << 3));
            #pragma unroll
            for (int ct = 0; ct < 4; ++ct)
                #pragma unroll
                for (int km = 0; km < 4; ++km)
                    acc[rtl][ct] = __builtin_amdgcn_mfma_f32_16x16x32_bf16(Af[km], Bf[ct][km], acc[rtl][ct], 0, 0, 0);
        }

        // epilogue: k chunks (ct<2) rope+softmax+kcs; v chunks (ct>=2) bias only.
        // slot o = (ct&1)*32 + rtl*16 + quad*4 + i  (same (c,row) enumeration for k and v)
        #pragma unroll
        for (int rtl = 0; rtl < 2; ++rtl)
            #pragma unroll
            for (int ct = 0; ct < 4; ++ct) {
                float x0 = acc[rtl][ct][0] + bias[ct];
                float x1 = acc[rtl][ct][1] + bias[ct];
                float x2 = acc[rtl][ct][2] + bias[ct];
                float x3 = acc[rtl][ct][3] + bias[ct];
                if (ct < 2) {
                    float p0 = __shfl_xor(x0, 1), p1 = __shfl_xor(x1, 1);
                    float p2 = __shfl_xor(x2, 1), p3 = __shfl_xor(x3, 1);
                    x0 = fmaf(p0, sgn, x0 * cvv); x1 = fmaf(p1, sgn, x1 * cvv);
                    x2 = fmaf(p2, sgn, x2 * cvv); x3 = fmaf(p3, sgn, x3 * cvv);
                    x0 = __expf(x0); x1 = __expf(x1); x2 = __expf(x2); x3 = __expf(x3);
                    float s0 = x0, s1 = x1, s2 = x2, s3 = x3;
                    s0 += __shfl_xor(s0, 1); s0 += __shfl_xor(s0, 2); s0 += __shfl_xor(s0, 4); s0 += __shfl_xor(s0, 8);
                    s1 += __shfl_xor(s1, 1); s1 += __shfl_xor(s1, 2); s1 += __shfl_xor(s1, 4); s1 += __shfl_xor(s1, 8);
                    s2 += __shfl_xor(s2, 1); s2 += __shfl_xor(s2, 2); s2 += __shfl_xor(s2, 4); s2 += __shfl_xor(s2, 8);
                    s3 += __shfl_xor(s3, 1); s3 += __shfl_xor(s3, 2); s3 += __shfl_xor(s3, 4); s3 += __shfl_xor(s3, 8);
                    x0 /= s0; x1 /= s1; x2 /= s2; x3 /= s3;
                    kcsacc += x0 + x1 + x2 + x3;
                }
                unsigned short* dst = (ct < 2) ? kbuf : vbuf;
                int o = (ct & 1) * 32 + rtl * 16 + quad * 4;      // o&7 in {0,4}
                *(uint2*)(dst + n * 64 + (((o >> 3) ^ (n & 7)) << 3) + (o & 7)) =
                    make_uint2(pk2(x0, x1), pk2(x2, x3));
            }

        // wave-local visibility: drain own ds_writes before cross-lane ds_reads
        asm volatile("s_waitcnt lgkmcnt(0)" ::: "memory");
        __builtin_amdgcn_sched_barrier(0);

        // kv partial over this pair's 64 slots: A = kbuf[n][slot], B = vbuf[n][slot]
        #pragma unroll
        for (int m = 0; m < 2; ++m) {
            int o = m * 32 + quad * 8;                            // o&7 == 0
            int off = (((o >> 3) ^ (n & 7)) << 3);
            short8 Ak = *(const short8*)(kbuf + n * 64 + off);
            short8 Bv = *(const short8*)(vbuf + n * 64 + off);
            kvacc = __builtin_amdgcn_mfma_f32_16x16x32_bf16(Ak, Bv, kvacc, 0, 0, 0);
        }
        // next pair's writes alias these reads (WAR on same LDS addrs) -> compiler keeps order;
        // same-wave DS ops execute in issue order.
    }

    // per-(block,wave) partials -> ws (no atomics; k_red sums 256 records per bh)
    kcsacc += __shfl_xor(kcsacc, 16); kcsacc += __shfl_xor(kcsacc, 32);
    float* part = ws + OFF_PART + ((long)blk * 4 + wave) * 272;
    #pragma unroll
    for (int r = 0; r < 4; ++r) part[(quad * 4 + r) * 16 + n] = kvacc[r];
    if (lane < 16) part[256 + n] = kcsacc;
}

// ---------------- reduce partials -> kv[32][16][16], kcs[32][16] ----------------
__global__ void k_red(float* __restrict__ ws) {
    int bh = blockIdx.x, t = threadIdx.x;
    if (t >= 272) return;
    const float* part = ws + OFF_PART + (long)bh * 256 * 272 + t;
    float s = 0.f;
    #pragma unroll 8
    for (int i = 0; i < 256; ++i) s += part[(long)i * 272];
    if (t < 256) ws[OFF_KV + bh * 256 + t] = s;
    else         ws[OFF_KCS + bh * 16 + (t - 256)] = s;
}

// ---------------- K3 (R3, exonerated): f = q + (q@kv)*Dinv, out = f@Wo^T + bo (all MFMA) ----------------
// 128 out-rows/block, 512 blocks. wave w: heads/out-chunks {2w, 2w+1}.
__global__ __launch_bounds__(256, 2) void k_out(const float* __restrict__ bo,
                                                float* __restrict__ ws,
                                                float* __restrict__ out) {
    __shared__ __align__(16) unsigned short tile[128 * 128];   // q then f (row-passed)
    const unsigned short* qws16 = (const unsigned short*)(ws + OFF_QWS);
    int t = threadIdx.x, blk = blockIdx.x;
    int wave = t >> 6, lane = t & 63, quad = lane >> 4, n = lane & 15;
    int b = blk >> 7;
    int sp0 = (blk & 127) * 128;

    // stage q tile: [row][col = h*16+j] bf16, swizzled
    #pragma unroll
    for (int i = 0; i < 16; ++i) {
        int idx = i * 256 + t;
        int h = idx >> 9, rr = (idx >> 2) & 127, seg = idx & 3;
        uint2 u = *(const uint2*)(qws16 + ((long)(b * 8 + h) * 16384 + sp0 + rr) * 16 + seg * 4);
        unsigned short* p = tile + rr * 128 + (((h * 2 + (seg >> 1)) ^ (rr & 7)) << 3) + (seg & 1) * 4;
        *(uint2*)p = u;
    }

    // B-frags: kv/kcs (block-diag halves) for heads 2w, 2w+1; Wo frags for out cols
    short8 Bkv[2], Bden[2];
    #pragma unroll
    for (int ct = 0; ct < 2; ++ct) {
        int h = 2 * wave + ct;
        const float* kvp = ws + OFF_KV + (b * 8 + h) * 256;
        const float* ksp = ws + OFF_KCS + (b * 8 + h) * 16;
        short8 bk8 = {0, 0, 0, 0, 0, 0, 0, 0}, bd8 = {0, 0, 0, 0, 0, 0, 0, 0};
        bool act = (ct == 0) ? (quad < 2) : (quad >= 2);
        int kbase = (ct == 0) ? quad * 8 : (quad - 2) * 8;
        if (act) {
            #pragma unroll
            for (int jj = 0; jj < 8; ++jj) {
                bk8[jj] = (short)f2bf(kvp[(kbase + jj) * 16 + n]);
                bd8[jj] = (short)f2bf(ksp[kbase + jj]);
            }
        }
        Bkv[ct] = bk8; Bden[ct] = bd8;
    }
    const short8* fo = (const short8*)((const unsigned short*)(ws + OFF_FRG_O));
    short8 Bo[2][4];
    #pragma unroll
    for (int ct = 0; ct < 2; ++ct)
        #pragma unroll
        for (int km = 0; km < 4; ++km)
            Bo[ct][km] = fo[((2 * wave + ct) * 4 + km) * 64 + lane];
    __syncthreads();

    // two passes over row-halves: compute f, overwrite tile in place
    #pragma unroll
    for (int pass = 0; pass < 2; ++pass) {
        unsigned short fh[4][2][4];
        #pragma unroll
        for (int rtl = 0; rtl < 4; ++rtl) {
            int rt = pass * 4 + rtl;
            int row = rt * 16 + n;
            short8 Af = *(const short8*)(tile + row * 128 + (((wave * 4 + quad) ^ (n & 7)) << 3));
            float4v P0 = __builtin_amdgcn_mfma_f32_16x16x32_bf16(Af, Bkv[0], (float4v){0.f,0.f,0.f,0.f}, 0, 0, 0);
            float4v P1 = __builtin_amdgcn_mfma_f32_16x16x32_bf16(Af, Bkv[1], (float4v){0.f,0.f,0.f,0.f}, 0, 0, 0);
            float4v D0 = __builtin_amdgcn_mfma_f32_16x16x32_bf16(Af, Bden[0], (float4v){0.f,0.f,0.f,0.f}, 0, 0, 0);
            float4v D1 = __builtin_amdgcn_mfma_f32_16x16x32_bf16(Af, Bden[1], (float4v){0.f,0.f,0.f,0.f}, 0, 0, 0);
            #pragma unroll
            for (int ct = 0; ct < 2; ++ct) {
                int cg = 2 * wave + ct;
                float4v P = ct ? P1 : P0;
                float4v D = ct ? D1 : D0;
                #pragma unroll
                for (int i = 0; i < 4; ++i) {
                    int rw = rt * 16 + quad * 4 + i;
                    int col = cg * 16 + n;
                    float qv = bf2f(tile[rw * 128 + (((col >> 3) ^ (rw & 7)) << 3) + (col & 7)]);
                    float inv = 1.0f / fmaxf(D[i], 1e-8f);
                    fh[rtl][ct][i] = f2bf(fmaf(P[i], inv, qv));
                }
            }
        }
        __syncthreads();   // all q-reads of this row-half done everywhere
        #pragma unroll
        for (int rtl = 0; rtl < 4; ++rtl)
            #pragma unroll
            for (int ct = 0; ct < 2; ++ct) {
                int cg = 2 * wave + ct;
                #pragma unroll
                for (int i = 0; i < 4; ++i) {
                    int rw = (pass * 4 + rtl) * 16 + quad * 4 + i;
                    int col = cg * 16 + n;
                    tile[rw * 128 + (((col >> 3) ^ (rw & 7)) << 3) + (col & 7)] = fh[rtl][ct][i];
                }
            }
    }
    __syncthreads();

    // out = f @ Wo^T + bo
    float4v acc[8][2];
    #pragma unroll
    for (int rt = 0; rt < 8; ++rt)
        #pragma unroll
        for (int ct = 0; ct < 2; ++ct) acc[rt][ct] = (float4v){0.f, 0.f, 0.f, 0.f};
    #pragma unroll
    for (int rt = 0; rt < 8; ++rt) {
        int row = rt * 16 + n;
        #pragma unroll
        for (int km = 0; km < 4; ++km) {
            short8 Af = *(const short8*)(tile + row * 128 + (((km * 4 + quad) ^ (n & 7)) << 3));
            acc[rt][0] = __builtin_amdgcn_mfma_f32_16x16x32_bf16(Af, Bo[0][km], acc[rt][0], 0, 0, 0);
            acc[rt][1] = __builtin_amdgcn_mfma_f32_16x16x32_bf16(Af, Bo[1][km], acc[rt][1], 0, 0, 0);
        }
    }
    #pragma unroll
    for (int rt = 0; rt < 8; ++rt)
        #pragma unroll
        for (int ct = 0; ct < 2; ++ct) {
            int cg = 2 * wave + ct;
            float bb = bo[cg * 16 + n];
            #pragma unroll
            for (int i = 0; i < 4; ++i) {
                float v = acc[rt][ct][i] + bb;
                float pv = qperm1(v);
                if ((n & 1) == 0) {
                    long rg = (long)b * 16384 + sp0 + rt * 16 + quad * 4 + i;
                    *(float2*)(out + rg * 128 + cg * 16 + n) = make_float2(v, pv);
                }
            }
        }
}

extern "C" void kernel_launch(void* const* d_in, const int* in_sizes, int n_in,
                              void* d_out, int out_size, void* d_ws, size_t ws_size,
                              hipStream_t stream) {
    (void)in_sizes; (void)n_in; (void)out_size; (void)ws_size;
    const float* edge = (const float*)d_in[1];
    const float* qd   = (const float*)d_in[2];
    const float* Wq   = (const float*)d_in[3];
    const float* bq   = (const float*)d_in[4];
    // d_in[0], d_in[5..8]: dead code in reference
    const float* Wk1  = (const float*)d_in[9];
    const float* bk1  = (const float*)d_in[10];
    const float* Wv1  = (const float*)d_in[11];
    const float* bv1  = (const float*)d_in[12];
    const float* Wo   = (const float*)d_in[13];
    const float* bo   = (const float*)d_in[14];
    float* ws  = (float*)d_ws;
    float* out = (float*)d_out;

    hipLaunchKernelGGL(k_prep, dim3(256),  dim3(256), 0, stream, Wq, Wk1, Wv1, Wo, ws);
    hipLaunchKernelGGL(k_q,    dim3(512),  dim3(256), 0, stream, qd, bq, ws);
    hipLaunchKernelGGL(k_kv,   dim3(2048), dim3(256), 0, stream, edge, bk1, bv1, ws);
    hipLaunchKernelGGL(k_red,  dim3(32),   dim3(320), 0, stream, ws);
    hipLaunchKernelGGL(k_out,  dim3(512),  dim3(256), 0, stream, bo, ws, out);
}

// Round 2
// 298.926 us; speedup vs baseline: 1.4381x; 1.0568x over previous
//
#include <hip/hip_runtime.h>
#include <hip/hip_bf16.h>
#include <math.h>

// B_T=32, T=8 -> B=4; N=2048, E=8192, D=128, H=8, dh=16
// Index algebra (HW-verified R1/R2): flat reshape g = s*8 + cg;
//   q:   h = u_in_batch>>11 (= t_idx), s' = node*8+cg, rope pos = node>>8
//   k/v: h = (u&65535)>>13, rope pos = (u&8191)>>10 (block-uniform, 128-row blocks)
// x_0/Wk0/Wv0 branch is DEAD (out overwritten by edge iteration).
// R7 (this round):
//   - k_kv: shfl_xor softmax -> DPP butterfly (qperm1/sum16, VALU not ds_swizzle);
//     per-rt phases (32-slot bufs, 1 kv MFMA each) -> LDS 40KB, acc[4];
//     __launch_bounds__(256,4) -> 4 blocks/CU (was 3); setprio(1) around GEMM MFMAs
//   - k_q: per-rt epilogue (acc 64->8 regs), (256,4)
//   - k_out: per-rt final epilogue, (256,3)
//   - k_red: 256 blocks x 32-record partials + atomicAdd (kv/kcs zeroed in k_prep)

typedef __attribute__((ext_vector_type(8))) short short8;
typedef __attribute__((ext_vector_type(4))) float float4v;

#define LN1E4_OVER8 1.1512925464970229f

// ws float offsets
#define OFF_QWS   0                    // q' bf16 [b][h][s'][16]: 8388608 shorts = 4194304 floats
#define OFF_FRG_Q 4194304              // Wq B-frags bf16: 16384 shorts = 8192 floats
#define OFF_FRG_O 4202496              // Wo B-frags bf16: 16384 shorts
#define OFF_BFRG  4210688              // Wk|Wv B-frags bf16 (16 chunks): 32768 shorts = 16384 floats
#define OFF_KV    4227072              // [b*8+h][16][16] floats (atomically accumulated)
#define OFF_KCS   4235264              // [b*8+h][16] floats (contiguous after OFF_KV)
#define OFF_PART  4235776              // 2048 blocks x 4 waves x 272 floats

__device__ __forceinline__ unsigned short f2bf(float f) {
    __hip_bfloat16 h = __float2bfloat16(f);          // RNE
    return *reinterpret_cast<unsigned short*>(&h);
}
__device__ __forceinline__ float bf2f(unsigned short s) {
    return __uint_as_float(((unsigned)s) << 16);
}
__device__ __forceinline__ unsigned pk2(float a, float b) {
    __hip_bfloat162 h = __float22bfloat162_rn(make_float2(a, b));   // a -> low 16, b -> high 16
    return *reinterpret_cast<unsigned*>(&h);
}
// DPP helpers (16-lane butterfly within one DPP row)
template<int C> __device__ __forceinline__ float dppadd(float x) {
    int r = __builtin_amdgcn_update_dpp(0, __float_as_int(x), C, 0xF, 0xF, true);
    return x + __int_as_float(r);
}
__device__ __forceinline__ float sum16(float x) {
    x = dppadd<0xB1>(x);    // xor1
    x = dppadd<0x4E>(x);    // xor2
    x = dppadd<0x141>(x);   // row_half_mirror (xor4-equivalent for reduce)
    x = dppadd<0x140>(x);   // row_mirror (xor8-equivalent)
    return x;
}
__device__ __forceinline__ float qperm1(float x) {  // value from lane n^1
    int r = __builtin_amdgcn_update_dpp(0, __float_as_int(x), 0xB1, 0xF, 0xF, true);
    return __int_as_float(r);
}

// ---------------- prep: Wq / Wo B-frags + combined Wk|Wv B-frag table + kv/kcs zero ----------------
// grid 290*256 = 74240 threads: [0,32768) Wq/Wo, [32768,65536) Wk|Wv, [65536,74240) zero kv/kcs
__global__ void k_prep(const float* __restrict__ Wq, const float* __restrict__ Wk1,
                       const float* __restrict__ Wv1, const float* __restrict__ Wo,
                       float* __restrict__ ws) {
    int i = blockIdx.x * 256 + threadIdx.x;
    if (i < 32768) {                      // Wq / Wo frags: B[k][n] = W[n][k], MFMA lane order
        int j = i & 16383;
        int jE = j & 7, lane = (j >> 3) & 63, km = (j >> 9) & 3, cg = j >> 11;
        int n = cg * 16 + (lane & 15);
        int kk = km * 32 + (lane >> 4) * 8 + jE;
        const float* W = (i < 16384) ? Wq : Wo;
        unsigned short* dst = (unsigned short*)(ws + ((i < 16384) ? OFF_FRG_Q : OFF_FRG_O));
        dst[j] = f2bf(W[n * 128 + kk]);
    } else if (i < 65536) {               // R2-verified combined table: cg<8 -> Wk1, else Wv1
        int j = i - 32768;                // 0..32767
        int jE = j & 7, lane = (j >> 3) & 63, km = (j >> 9) & 3, cg = j >> 11;
        int n = cg * 16 + (lane & 15);
        int k = km * 32 + (lane >> 4) * 8 + jE;
        float w = (cg < 8) ? Wk1[n * 128 + k] : Wv1[(n - 128) * 128 + k];
        ((unsigned short*)(ws + OFF_BFRG))[j] = f2bf(w);
    } else {                              // zero kv[32][256] + kcs[32][16] (8704 floats, contiguous)
        int j = i - 65536;
        if (j < 8704) ws[OFF_KV + j] = 0.f;
    }
}

// ---------------- K1 (R7): Q MFMA GEMM + softmax(16) + rope -> bf16 qws, per-rt epilogue ----------------
// 128 rows/block, 512 blocks. wave w owns chunks {2w, 2w+1}.
__global__ __launch_bounds__(256, 4) void k_q(const float* __restrict__ qd,
                                              const float* __restrict__ bq,
                                              float* __restrict__ ws) {
    __shared__ __align__(16) unsigned short aT[128 * 128];
    unsigned* qws32 = (unsigned*)(ws + OFF_QWS);
    int t = threadIdx.x, blk = blockIdx.x;
    int wave = t >> 6, lane = t & 63, quad = lane >> 4, n = lane & 15;
    long base = (long)blk * 128;
    int b = blk >> 7;
    int h = (blk & 127) >> 4;
    int s0 = (blk & 15) * 1024;
    int t1 = (blk & 15) >> 1;           // rope position (block-uniform)

    const short8* fq = (const short8*)((const unsigned short*)(ws + OFF_FRG_Q));
    short8 Bf[2][4];
    #pragma unroll
    for (int ct = 0; ct < 2; ++ct)
        #pragma unroll
        for (int km = 0; km < 4; ++km)
            Bf[ct][km] = fq[((2 * wave + ct) * 4 + km) * 64 + lane];

    #pragma unroll
    for (int i = 0; i < 16; ++i) {
        int idx = i * 256 + t;
        int row = idx >> 5, c4 = idx & 31;
        float4 v = ((const float4*)qd)[(base + row) * 32 + c4];
        unsigned short* p = aT + row * 128 + (((c4 >> 1) ^ (row & 7)) << 3) + (c4 & 1) * 4;
        *(uint2*)p = make_uint2(pk2(v.x, v.y), pk2(v.z, v.w));
    }
    __syncthreads();

    float fr = __expf(-LN1E4_OVER8 * (float)(n >> 1));
    float sa, ca; __sincosf((float)t1 * fr, &sa, &ca);
    float sgn = (n & 1) ? sa : -sa;
    float bias0 = bq[(2 * wave) * 16 + n];
    float bias1 = bq[(2 * wave + 1) * 16 + n];

    #pragma unroll
    for (int rt = 0; rt < 8; ++rt) {
        float4v a0 = (float4v){0.f, 0.f, 0.f, 0.f};
        float4v a1 = (float4v){0.f, 0.f, 0.f, 0.f};
        int row = rt * 16 + n;
        #pragma unroll
        for (int km = 0; km < 4; ++km) {
            short8 Af = *(const short8*)(aT + row * 128 + (((km * 4 + quad) ^ (n & 7)) << 3));
            a0 = __builtin_amdgcn_mfma_f32_16x16x32_bf16(Af, Bf[0][km], a0, 0, 0, 0);
            a1 = __builtin_amdgcn_mfma_f32_16x16x32_bf16(Af, Bf[1][km], a1, 0, 0, 0);
        }
        #pragma unroll
        for (int ct = 0; ct < 2; ++ct) {
            int cg = 2 * wave + ct;
            float bias = ct ? bias1 : bias0;
            float4v x = ct ? a1 : a0;
            #pragma unroll
            for (int i = 0; i < 4; ++i) {
                float e = __expf(x[i] + bias);          // logits ~N(0,0.23): exp-safe
                float s = sum16(e);
                float q = e / s;
                float r = fmaf(qperm1(q), sgn, q * ca); // rope post-softmax
                unsigned pkd = ((unsigned)f2bf(qperm1(r)) << 16) | (unsigned)f2bf(r);
                if ((n & 1) == 0) {
                    int sp = s0 + (rt * 16 + quad * 4 + i) * 8 + cg;
                    long qoff = ((long)(b * 8 + h) * 16384 + sp) * 16 + n;  // shorts
                    qws32[qoff >> 1] = pkd;
                }
            }
        }
    }
}

// ---------------- K2 (R7): edge K/V MFMA + DPP rope/softmax + per-rt wave-local kv MFMA ----------------
// 128 rows/block, 2048 blocks. wave w owns k-chunks {2w,2w+1} AND v-chunks {2w,2w+1}.
// Per rt: 16 GEMM MFMAs -> epilogue (DPP softmax) -> 32-slot k/v bufs -> 1 kv MFMA.
__global__ __launch_bounds__(256, 4) void k_kv(const float* __restrict__ ea,
                                               const float* __restrict__ bk,
                                               const float* __restrict__ bv,
                                               float* __restrict__ ws) {
    __shared__ __align__(16) char smem[40960];              // 32KB aT + 4 x 2KB wave bufs
    unsigned short* aT = (unsigned short*)smem;             // [128][128] bf16 XOR-swizzled

    int t = threadIdx.x, blk = blockIdx.x;
    int wave = t >> 6, lane = t & 63, quad = lane >> 4, n = lane & 15;
    unsigned short* kbuf = (unsigned short*)(smem + 32768) + wave * 1024;  // [16][32] bf16, 2-bit granule XOR
    unsigned short* vbuf = kbuf + 512;                                     // [16][32]
    long base = (long)blk * 128;
    int sl = (blk & 511) << 7;                    // row within batch
    int t2 = (sl & 8191) >> 10;                   // block-uniform rope timestep

    // stage A tile fp32 -> bf16 LDS (verified swizzle, unchanged)
    #pragma unroll
    for (int i = 0; i < 16; ++i) {
        int idx = i * 256 + t;
        int row = idx >> 5, c4 = idx & 31;
        float4 v = ((const float4*)ea)[(base + row) * 32 + c4];
        unsigned short* p = aT + row * 128 + (((c4 >> 1) ^ (row & 7)) << 3) + (c4 & 1) * 4;
        *(uint2*)p = make_uint2(pk2(v.x, v.y), pk2(v.z, v.w));
    }

    // B fragments: ct0,1 = Wk chunks 2w,2w+1 ; ct2,3 = Wv chunks 2w,2w+1 (table: cg<8 k, cg>=8 v)
    const short8* bfrag = (const short8*)((const unsigned short*)(ws + OFF_BFRG));
    short8 Bf[4][4];
    #pragma unroll
    for (int ct = 0; ct < 4; ++ct) {
        int cg = (ct < 2) ? (2 * wave + ct) : (8 + 2 * wave + (ct - 2));
        #pragma unroll
        for (int km = 0; km < 4; ++km)
            Bf[ct][km] = bfrag[(cg * 4 + km) * 64 + lane];
    }

    float bias[4];
    #pragma unroll
    for (int ct = 0; ct < 4; ++ct)
        bias[ct] = (ct < 2) ? bk[(2 * wave + ct) * 16 + n] : bv[(2 * wave + ct - 2) * 16 + n];
    float fr = __expf(-LN1E4_OVER8 * (float)(n >> 1));
    float sv, cvv; __sincosf((float)t2 * fr, &sv, &cvv);
    float sgn = (n & 1) ? sv : -sv;   // rope: out = x*cos + partner*sgn
    float kcsacc = 0.f;
    float4v kvacc = (float4v){0.f, 0.f, 0.f, 0.f};

    __syncthreads();                  // the ONLY barrier: aT staged, never overwritten

    #pragma unroll
    for (int rt = 0; rt < 8; ++rt) {
        // GEMM rows [rt*16, rt*16+16): acc[4] = 16 regs
        float4v acc[4];
        #pragma unroll
        for (int ct = 0; ct < 4; ++ct) acc[ct] = (float4v){0.f, 0.f, 0.f, 0.f};

        int row = rt * 16 + n;
        short8 Af[4];
        #pragma unroll
        for (int km = 0; km < 4; ++km)
            Af[km] = *(const short8*)(aT + row * 128 + (((km * 4 + quad) ^ (n & 7)) << 3));
        __builtin_amdgcn_s_setprio(1);
        #pragma unroll
        for (int ct = 0; ct < 4; ++ct)
            #pragma unroll
            for (int km = 0; km < 4; ++km)
                acc[ct] = __builtin_amdgcn_mfma_f32_16x16x32_bf16(Af[km], Bf[ct][km], acc[ct], 0, 0, 0);
        __builtin_amdgcn_s_setprio(0);

        // epilogue: k chunks (ct<2) rope+softmax+kcs via DPP; v chunks (ct>=2) bias only.
        // local slot o = (ct&1)*16 + quad*4 + i  (same (chunk,row) enumeration for k and v)
        #pragma unroll
        for (int ct = 0; ct < 4; ++ct) {
            float x0 = acc[ct][0] + bias[ct];
            float x1 = acc[ct][1] + bias[ct];
            float x2 = acc[ct][2] + bias[ct];
            float x3 = acc[ct][3] + bias[ct];
            if (ct < 2) {
                // rope pairs = adjacent cols = lane^1 (quad_perm DPP), softmax over 16 cols (DPP butterfly)
                x0 = fmaf(qperm1(x0), sgn, x0 * cvv); x1 = fmaf(qperm1(x1), sgn, x1 * cvv);
                x2 = fmaf(qperm1(x2), sgn, x2 * cvv); x3 = fmaf(qperm1(x3), sgn, x3 * cvv);
                x0 = __expf(x0); x1 = __expf(x1); x2 = __expf(x2); x3 = __expf(x3);
                float s0 = sum16(x0), s1 = sum16(x1), s2 = sum16(x2), s3 = sum16(x3);
                x0 /= s0; x1 /= s1; x2 /= s2; x3 /= s3;
                kcsacc += x0 + x1 + x2 + x3;
            }
            unsigned short* dst = (ct < 2) ? kbuf : vbuf;
            int o = (ct & 1) * 16 + quad * 4;                 // o&7 in {0,4}, granule o>>3 in 0..3
            *(uint2*)(dst + n * 32 + (((o >> 3) ^ (n & 3)) << 3) + (o & 7)) =
                make_uint2(pk2(x0, x1), pk2(x2, x3));
        }

        // wave-local visibility: drain own ds_writes before cross-lane ds_reads
        asm volatile("s_waitcnt lgkmcnt(0)" ::: "memory");
        __builtin_amdgcn_sched_barrier(0);

        // kv partial over this rt's 32 slots: A = kbuf[n][slot], B = vbuf[n][slot]
        {
            int off = ((quad ^ (n & 3)) << 3);                // slot group quad*8, swizzled granule
            short8 Ak = *(const short8*)(kbuf + n * 32 + off);
            short8 Bv = *(const short8*)(vbuf + n * 32 + off);
            kvacc = __builtin_amdgcn_mfma_f32_16x16x32_bf16(Ak, Bv, kvacc, 0, 0, 0);
        }
        // next rt's ds_writes alias these ds_reads (WAR, same wave): DS pipe is in-order per wave.
    }

    // per-(block,wave) partials -> ws (no atomics here; k_red accumulates)
    kcsacc += __shfl_xor(kcsacc, 16); kcsacc += __shfl_xor(kcsacc, 32);
    float* part = ws + OFF_PART + ((long)blk * 4 + wave) * 272;
    #pragma unroll
    for (int r = 0; r < 4; ++r) part[(quad * 4 + r) * 16 + n] = kvacc[r];
    if (lane < 16) part[256 + n] = kcsacc;
}

// ---------------- reduce partials -> kv[32][16][16], kcs[32][16] (atomic, 8x parallel) ----------------
// 256 blocks: bh = blk>>3, record group g = blk&7 (32 records each). kv/kcs pre-zeroed in k_prep.
__global__ void k_red(float* __restrict__ ws) {
    int blk = blockIdx.x, t = threadIdx.x;
    if (t >= 272) return;
    int bh = blk >> 3, g = blk & 7;
    const float* part = ws + OFF_PART + (long)bh * 256 * 272 + (long)g * 32 * 272 + t;
    float s = 0.f;
    #pragma unroll 8
    for (int i = 0; i < 32; ++i) s += part[(long)i * 272];
    float* dst = (t < 256) ? (ws + OFF_KV + bh * 256 + t)
                           : (ws + OFF_KCS + bh * 16 + (t - 256));
    atomicAdd(dst, s);
}

// ---------------- K3 (R7): f = q + (q@kv)*Dinv, out = f@Wo^T + bo (all MFMA) ----------------
// 128 out-rows/block, 512 blocks. wave w: heads/out-chunks {2w, 2w+1}.
__global__ __launch_bounds__(256, 3) void k_out(const float* __restrict__ bo,
                                                float* __restrict__ ws,
                                                float* __restrict__ out) {
    __shared__ __align__(16) unsigned short tile[128 * 128];   // q then f (row-passed)
    const unsigned short* qws16 = (const unsigned short*)(ws + OFF_QWS);
    int t = threadIdx.x, blk = blockIdx.x;
    int wave = t >> 6, lane = t & 63, quad = lane >> 4, n = lane & 15;
    int b = blk >> 7;
    int sp0 = (blk & 127) * 128;

    // stage q tile: [row][col = h*16+j] bf16, swizzled
    #pragma unroll
    for (int i = 0; i < 16; ++i) {
        int idx = i * 256 + t;
        int h = idx >> 9, rr = (idx >> 2) & 127, seg = idx & 3;
        uint2 u = *(const uint2*)(qws16 + ((long)(b * 8 + h) * 16384 + sp0 + rr) * 16 + seg * 4);
        unsigned short* p = tile + rr * 128 + (((h * 2 + (seg >> 1)) ^ (rr & 7)) << 3) + (seg & 1) * 4;
        *(uint2*)p = u;
    }

    // B-frags: kv/kcs (block-diag halves) for heads 2w, 2w+1; Wo frags for out cols
    short8 Bkv[2], Bden[2];
    #pragma unroll
    for (int ct = 0; ct < 2; ++ct) {
        int h = 2 * wave + ct;
        const float* kvp = ws + OFF_KV + (b * 8 + h) * 256;
        const float* ksp = ws + OFF_KCS + (b * 8 + h) * 16;
        short8 bk8 = {0, 0, 0, 0, 0, 0, 0, 0}, bd8 = {0, 0, 0, 0, 0, 0, 0, 0};
        bool act = (ct == 0) ? (quad < 2) : (quad >= 2);
        int kbase = (ct == 0) ? quad * 8 : (quad - 2) * 8;
        if (act) {
            #pragma unroll
            for (int jj = 0; jj < 8; ++jj) {
                bk8[jj] = (short)f2bf(kvp[(kbase + jj) * 16 + n]);
                bd8[jj] = (short)f2bf(ksp[kbase + jj]);
            }
        }
        Bkv[ct] = bk8; Bden[ct] = bd8;
    }
    const short8* fo = (const short8*)((const unsigned short*)(ws + OFF_FRG_O));
    short8 Bo[2][4];
    #pragma unroll
    for (int ct = 0; ct < 2; ++ct)
        #pragma unroll
        for (int km = 0; km < 4; ++km)
            Bo[ct][km] = fo[((2 * wave + ct) * 4 + km) * 64 + lane];
    __syncthreads();

    // two passes over row-halves: compute f, overwrite tile in place
    #pragma unroll
    for (int pass = 0; pass < 2; ++pass) {
        unsigned short fh[4][2][4];
        #pragma unroll
        for (int rtl = 0; rtl < 4; ++rtl) {
            int rt = pass * 4 + rtl;
            int row = rt * 16 + n;
            short8 Af = *(const short8*)(tile + row * 128 + (((wave * 4 + quad) ^ (n & 7)) << 3));
            float4v P0 = __builtin_amdgcn_mfma_f32_16x16x32_bf16(Af, Bkv[0], (float4v){0.f,0.f,0.f,0.f}, 0, 0, 0);
            float4v P1 = __builtin_amdgcn_mfma_f32_16x16x32_bf16(Af, Bkv[1], (float4v){0.f,0.f,0.f,0.f}, 0, 0, 0);
            float4v D0 = __builtin_amdgcn_mfma_f32_16x16x32_bf16(Af, Bden[0], (float4v){0.f,0.f,0.f,0.f}, 0, 0, 0);
            float4v D1 = __builtin_amdgcn_mfma_f32_16x16x32_bf16(Af, Bden[1], (float4v){0.f,0.f,0.f,0.f}, 0, 0, 0);
            #pragma unroll
            for (int ct = 0; ct < 2; ++ct) {
                int cg = 2 * wave + ct;
                float4v P = ct ? P1 : P0;
                float4v D = ct ? D1 : D0;
                #pragma unroll
                for (int i = 0; i < 4; ++i) {
                    int rw = rt * 16 + quad * 4 + i;
                    int col = cg * 16 + n;
                    float qv = bf2f(tile[rw * 128 + (((col >> 3) ^ (rw & 7)) << 3) + (col & 7)]);
                    float inv = 1.0f / fmaxf(D[i], 1e-8f);
                    fh[rtl][ct][i] = f2bf(fmaf(P[i], inv, qv));
                }
            }
        }
        __syncthreads();   // all q-reads of this row-half done everywhere
        #pragma unroll
        for (int rtl = 0; rtl < 4; ++rtl)
            #pragma unroll
            for (int ct = 0; ct < 2; ++ct) {
                int cg = 2 * wave + ct;
                #pragma unroll
                for (int i = 0; i < 4; ++i) {
                    int rw = (pass * 4 + rtl) * 16 + quad * 4 + i;
                    int col = cg * 16 + n;
                    tile[rw * 128 + (((col >> 3) ^ (rw & 7)) << 3) + (col & 7)] = fh[rtl][ct][i];
                }
            }
    }
    __syncthreads();

    // out = f @ Wo^T + bo, per-rt epilogue (acc 64->8 live regs)
    float bb0 = bo[(2 * wave) * 16 + n];
    float bb1 = bo[(2 * wave + 1) * 16 + n];
    #pragma unroll
    for (int rt = 0; rt < 8; ++rt) {
        float4v a0 = (float4v){0.f, 0.f, 0.f, 0.f};
        float4v a1 = (float4v){0.f, 0.f, 0.f, 0.f};
        int row = rt * 16 + n;
        #pragma unroll
        for (int km = 0; km < 4; ++km) {
            short8 Af = *(const short8*)(tile + row * 128 + (((km * 4 + quad) ^ (n & 7)) << 3));
            a0 = __builtin_amdgcn_mfma_f32_16x16x32_bf16(Af, Bo[0][km], a0, 0, 0, 0);
            a1 = __builtin_amdgcn_mfma_f32_16x16x32_bf16(Af, Bo[1][km], a1, 0, 0, 0);
        }
        #pragma unroll
        for (int ct = 0; ct < 2; ++ct) {
            int cg = 2 * wave + ct;
            float bb = ct ? bb1 : bb0;
            float4v a = ct ? a1 : a0;
            #pragma unroll
            for (int i = 0; i < 4; ++i) {
                float v = a[i] + bb;
                float pv = qperm1(v);
                if ((n & 1) == 0) {
                    long rg = (long)b * 16384 + sp0 + rt * 16 + quad * 4 + i;
                    *(float2*)(out + rg * 128 + cg * 16 + n) = make_float2(v, pv);
                }
            }
        }
    }
}

extern "C" void kernel_launch(void* const* d_in, const int* in_sizes, int n_in,
                              void* d_out, int out_size, void* d_ws, size_t ws_size,
                              hipStream_t stream) {
    (void)in_sizes; (void)n_in; (void)out_size; (void)ws_size;
    const float* edge = (const float*)d_in[1];
    const float* qd   = (const float*)d_in[2];
    const float* Wq   = (const float*)d_in[3];
    const float* bq   = (const float*)d_in[4];
    // d_in[0], d_in[5..8]: dead code in reference
    const float* Wk1  = (const float*)d_in[9];
    const float* bk1  = (const float*)d_in[10];
    const float* Wv1  = (const float*)d_in[11];
    const float* bv1  = (const float*)d_in[12];
    const float* Wo   = (const float*)d_in[13];
    const float* bo   = (const float*)d_in[14];
    float* ws  = (float*)d_ws;
    float* out = (float*)d_out;

    hipLaunchKernelGGL(k_prep, dim3(290),  dim3(256), 0, stream, Wq, Wk1, Wv1, Wo, ws);
    hipLaunchKernelGGL(k_q,    dim3(512),  dim3(256), 0, stream, qd, bq, ws);
    hipLaunchKernelGGL(k_kv,   dim3(2048), dim3(256), 0, stream, edge, bk1, bv1, ws);
    hipLaunchKernelGGL(k_red,  dim3(256),  dim3(320), 0, stream, ws);
    hipLaunchKernelGGL(k_out,  dim3(512),  dim3(256), 0, stream, bo, ws, out);
}

// Round 3
// 283.006 us; speedup vs baseline: 1.5190x; 1.0563x over previous
//
#include <hip/hip_runtime.h>
#include <hip/hip_bf16.h>
#include <math.h>

// B_T=32, T=8 -> B=4; N=2048, E=8192, D=128, H=8, dh=16
// Index algebra (HW-verified R1/R2): flat reshape g = s*8 + cg;
//   q:   h = u_in_batch>>11 (= t_idx), s' = node*8+cg, rope pos = node>>8
//   k/v: h = (u&65535)>>13, rope pos = (u&8191)>>10 (block-uniform, 128-row blocks)
// x_0/Wk0/Wv0 branch is DEAD (out overwritten by edge iteration).
// R8 (this round):
//   - k_q FUSED into k_kv -> k_main (2560 blocks, 1 q-block per 4 kv-blocks interleave):
//     q-work (no data dep on kv-work) now overlaps instead of serializing (~25% machine
//     fill standalone before). Same 40KB smem block reused by both paths.
//   - k_out: 64-row blocks, 1024 blocks x (256,4) = exactly full residency, no tail
//   - softmax/Dinv divides -> v_rcp_f32 (1 ulp; output is bf16-rounded anyway)

typedef __attribute__((ext_vector_type(8))) short short8;
typedef __attribute__((ext_vector_type(4))) float float4v;

#define LN1E4_OVER8 1.1512925464970229f

// ws float offsets
#define OFF_QWS   0                    // q' bf16 [b][h][s'][16]: 8388608 shorts = 4194304 floats
#define OFF_FRG_Q 4194304              // Wq B-frags bf16: 16384 shorts = 8192 floats
#define OFF_FRG_O 4202496              // Wo B-frags bf16: 16384 shorts
#define OFF_BFRG  4210688              // Wk|Wv B-frags bf16 (16 chunks): 32768 shorts = 16384 floats
#define OFF_KV    4227072              // [b*8+h][16][16] floats (atomically accumulated)
#define OFF_KCS   4235264              // [b*8+h][16] floats (contiguous after OFF_KV)
#define OFF_PART  4235776              // 2048 blocks x 4 waves x 272 floats

__device__ __forceinline__ unsigned short f2bf(float f) {
    __hip_bfloat16 h = __float2bfloat16(f);          // RNE
    return *reinterpret_cast<unsigned short*>(&h);
}
__device__ __forceinline__ float bf2f(unsigned short s) {
    return __uint_as_float(((unsigned)s) << 16);
}
__device__ __forceinline__ unsigned pk2(float a, float b) {
    __hip_bfloat162 h = __float22bfloat162_rn(make_float2(a, b));   // a -> low 16, b -> high 16
    return *reinterpret_cast<unsigned*>(&h);
}
__device__ __forceinline__ float frcp(float x) {     // v_rcp_f32: ~1 ulp, plenty for bf16 outputs
    return __builtin_amdgcn_rcpf(x);
}
// DPP helpers (16-lane butterfly within one DPP row)
template<int C> __device__ __forceinline__ float dppadd(float x) {
    int r = __builtin_amdgcn_update_dpp(0, __float_as_int(x), C, 0xF, 0xF, true);
    return x + __int_as_float(r);
}
__device__ __forceinline__ float sum16(float x) {
    x = dppadd<0xB1>(x);    // xor1
    x = dppadd<0x4E>(x);    // xor2
    x = dppadd<0x141>(x);   // row_half_mirror
    x = dppadd<0x140>(x);   // row_mirror
    return x;
}
__device__ __forceinline__ float qperm1(float x) {  // value from lane n^1
    int r = __builtin_amdgcn_update_dpp(0, __float_as_int(x), 0xB1, 0xF, 0xF, true);
    return __int_as_float(r);
}

// ---------------- prep: Wq / Wo B-frags + combined Wk|Wv B-frag table + kv/kcs zero ----------------
// grid 290*256 = 74240 threads: [0,32768) Wq/Wo, [32768,65536) Wk|Wv, [65536,74240) zero kv/kcs
__global__ void k_prep(const float* __restrict__ Wq, const float* __restrict__ Wk1,
                       const float* __restrict__ Wv1, const float* __restrict__ Wo,
                       float* __restrict__ ws) {
    int i = blockIdx.x * 256 + threadIdx.x;
    if (i < 32768) {                      // Wq / Wo frags: B[k][n] = W[n][k], MFMA lane order
        int j = i & 16383;
        int jE = j & 7, lane = (j >> 3) & 63, km = (j >> 9) & 3, cg = j >> 11;
        int n = cg * 16 + (lane & 15);
        int kk = km * 32 + (lane >> 4) * 8 + jE;
        const float* W = (i < 16384) ? Wq : Wo;
        unsigned short* dst = (unsigned short*)(ws + ((i < 16384) ? OFF_FRG_Q : OFF_FRG_O));
        dst[j] = f2bf(W[n * 128 + kk]);
    } else if (i < 65536) {               // R2-verified combined table: cg<8 -> Wk1, else Wv1
        int j = i - 32768;                // 0..32767
        int jE = j & 7, lane = (j >> 3) & 63, km = (j >> 9) & 3, cg = j >> 11;
        int n = cg * 16 + (lane & 15);
        int k = km * 32 + (lane >> 4) * 8 + jE;
        float w = (cg < 8) ? Wk1[n * 128 + k] : Wv1[(n - 128) * 128 + k];
        ((unsigned short*)(ws + OFF_BFRG))[j] = f2bf(w);
    } else {                              // zero kv[32][256] + kcs[32][16] (8704 floats, contiguous)
        int j = i - 65536;
        if (j < 8704) ws[OFF_KV + j] = 0.f;
    }
}

// ---------------- K1 (R8): fused q-GEMM + edge-K/V pipeline, 2560 blocks ----------------
// blocks with g%5==4 (512 of them): q path, q_blk = g/5.
// other blocks (2048): kv path, kv_blk = g - g/5.
__global__ __launch_bounds__(256, 4) void k_main(const float* __restrict__ ea,
                                                 const float* __restrict__ bk,
                                                 const float* __restrict__ bv,
                                                 const float* __restrict__ qd,
                                                 const float* __restrict__ bq,
                                                 float* __restrict__ ws) {
    __shared__ __align__(16) char smem[40960];              // kv: 32KB aT + 4x2KB; q: 32KB aT
    int t = threadIdx.x;
    int wave = t >> 6, lane = t & 63, quad = lane >> 4, n = lane & 15;
    int g = blockIdx.x;

    if (g % 5 == 4) {
        // ---------------- q path (R3-verified dataflow, per-rt epilogue) ----------------
        int blk = g / 5;                                    // 0..511
        unsigned short* aT = (unsigned short*)smem;
        unsigned* qws32 = (unsigned*)(ws + OFF_QWS);
        long base = (long)blk * 128;
        int b = blk >> 7;
        int h = (blk & 127) >> 4;
        int s0 = (blk & 15) * 1024;
        int t1 = (blk & 15) >> 1;       // rope position (block-uniform)

        const short8* fq = (const short8*)((const unsigned short*)(ws + OFF_FRG_Q));
        short8 Bf[2][4];
        #pragma unroll
        for (int ct = 0; ct < 2; ++ct)
            #pragma unroll
            for (int km = 0; km < 4; ++km)
                Bf[ct][km] = fq[((2 * wave + ct) * 4 + km) * 64 + lane];

        #pragma unroll
        for (int i = 0; i < 16; ++i) {
            int idx = i * 256 + t;
            int row = idx >> 5, c4 = idx & 31;
            float4 v = ((const float4*)qd)[(base + row) * 32 + c4];
            unsigned short* p = aT + row * 128 + (((c4 >> 1) ^ (row & 7)) << 3) + (c4 & 1) * 4;
            *(uint2*)p = make_uint2(pk2(v.x, v.y), pk2(v.z, v.w));
        }
        __syncthreads();

        float fr = __expf(-LN1E4_OVER8 * (float)(n >> 1));
        float sa, ca; __sincosf((float)t1 * fr, &sa, &ca);
        float sgn = (n & 1) ? sa : -sa;
        float bias0 = bq[(2 * wave) * 16 + n];
        float bias1 = bq[(2 * wave + 1) * 16 + n];

        #pragma unroll
        for (int rt = 0; rt < 8; ++rt) {
            float4v a0 = (float4v){0.f, 0.f, 0.f, 0.f};
            float4v a1 = (float4v){0.f, 0.f, 0.f, 0.f};
            int row = rt * 16 + n;
            __builtin_amdgcn_s_setprio(1);
            #pragma unroll
            for (int km = 0; km < 4; ++km) {
                short8 Af = *(const short8*)(aT + row * 128 + (((km * 4 + quad) ^ (n & 7)) << 3));
                a0 = __builtin_amdgcn_mfma_f32_16x16x32_bf16(Af, Bf[0][km], a0, 0, 0, 0);
                a1 = __builtin_amdgcn_mfma_f32_16x16x32_bf16(Af, Bf[1][km], a1, 0, 0, 0);
            }
            __builtin_amdgcn_s_setprio(0);
            #pragma unroll
            for (int ct = 0; ct < 2; ++ct) {
                int cg = 2 * wave + ct;
                float bias = ct ? bias1 : bias0;
                float4v x = ct ? a1 : a0;
                #pragma unroll
                for (int i = 0; i < 4; ++i) {
                    float e = __expf(x[i] + bias);          // logits ~N(0,0.23): exp-safe
                    float q = e * frcp(sum16(e));
                    float r = fmaf(qperm1(q), sgn, q * ca); // rope post-softmax
                    unsigned pkd = ((unsigned)f2bf(qperm1(r)) << 16) | (unsigned)f2bf(r);
                    if ((n & 1) == 0) {
                        int sp = s0 + (rt * 16 + quad * 4 + i) * 8 + cg;
                        long qoff = ((long)(b * 8 + h) * 16384 + sp) * 16 + n;  // shorts
                        qws32[qoff >> 1] = pkd;
                    }
                }
            }
        }
        return;
    }

    // ---------------- kv path (R7 structure: per-rt phases, wave-local kv MFMA) ----------------
    int blk = g - g / 5;                                    // 0..2047
    unsigned short* aT = (unsigned short*)smem;             // [128][128] bf16 XOR-swizzled
    unsigned short* kbuf = (unsigned short*)(smem + 32768) + wave * 1024;  // [16][32] bf16, 2-bit granule XOR
    unsigned short* vbuf = kbuf + 512;                                     // [16][32]
    long base = (long)blk * 128;
    int sl = (blk & 511) << 7;                    // row within batch
    int t2 = (sl & 8191) >> 10;                   // block-uniform rope timestep

    // stage A tile fp32 -> bf16 LDS (verified swizzle, unchanged)
    #pragma unroll
    for (int i = 0; i < 16; ++i) {
        int idx = i * 256 + t;
        int row = idx >> 5, c4 = idx & 31;
        float4 v = ((const float4*)ea)[(base + row) * 32 + c4];
        unsigned short* p = aT + row * 128 + (((c4 >> 1) ^ (row & 7)) << 3) + (c4 & 1) * 4;
        *(uint2*)p = make_uint2(pk2(v.x, v.y), pk2(v.z, v.w));
    }

    // B fragments: ct0,1 = Wk chunks 2w,2w+1 ; ct2,3 = Wv chunks 2w,2w+1 (table: cg<8 k, cg>=8 v)
    const short8* bfrag = (const short8*)((const unsigned short*)(ws + OFF_BFRG));
    short8 Bf[4][4];
    #pragma unroll
    for (int ct = 0; ct < 4; ++ct) {
        int cg = (ct < 2) ? (2 * wave + ct) : (8 + 2 * wave + (ct - 2));
        #pragma unroll
        for (int km = 0; km < 4; ++km)
            Bf[ct][km] = bfrag[(cg * 4 + km) * 64 + lane];
    }

    float bias[4];
    #pragma unroll
    for (int ct = 0; ct < 4; ++ct)
        bias[ct] = (ct < 2) ? bk[(2 * wave + ct) * 16 + n] : bv[(2 * wave + ct - 2) * 16 + n];
    float fr = __expf(-LN1E4_OVER8 * (float)(n >> 1));
    float sv, cvv; __sincosf((float)t2 * fr, &sv, &cvv);
    float sgn = (n & 1) ? sv : -sv;   // rope: out = x*cos + partner*sgn
    float kcsacc = 0.f;
    float4v kvacc = (float4v){0.f, 0.f, 0.f, 0.f};

    __syncthreads();                  // the ONLY barrier: aT staged, never overwritten

    #pragma unroll
    for (int rt = 0; rt < 8; ++rt) {
        // GEMM rows [rt*16, rt*16+16): acc[4] = 16 regs
        float4v acc[4];
        #pragma unroll
        for (int ct = 0; ct < 4; ++ct) acc[ct] = (float4v){0.f, 0.f, 0.f, 0.f};

        int row = rt * 16 + n;
        short8 Af[4];
        #pragma unroll
        for (int km = 0; km < 4; ++km)
            Af[km] = *(const short8*)(aT + row * 128 + (((km * 4 + quad) ^ (n & 7)) << 3));
        __builtin_amdgcn_s_setprio(1);
        #pragma unroll
        for (int ct = 0; ct < 4; ++ct)
            #pragma unroll
            for (int km = 0; km < 4; ++km)
                acc[ct] = __builtin_amdgcn_mfma_f32_16x16x32_bf16(Af[km], Bf[ct][km], acc[ct], 0, 0, 0);
        __builtin_amdgcn_s_setprio(0);

        // epilogue: k chunks (ct<2) rope+softmax+kcs via DPP; v chunks (ct>=2) bias only.
        // local slot o = (ct&1)*16 + quad*4 + i  (same (chunk,row) enumeration for k and v)
        #pragma unroll
        for (int ct = 0; ct < 4; ++ct) {
            float x0 = acc[ct][0] + bias[ct];
            float x1 = acc[ct][1] + bias[ct];
            float x2 = acc[ct][2] + bias[ct];
            float x3 = acc[ct][3] + bias[ct];
            if (ct < 2) {
                // rope pairs = adjacent cols = lane^1 (quad_perm DPP), softmax over 16 cols (DPP butterfly)
                x0 = fmaf(qperm1(x0), sgn, x0 * cvv); x1 = fmaf(qperm1(x1), sgn, x1 * cvv);
                x2 = fmaf(qperm1(x2), sgn, x2 * cvv); x3 = fmaf(qperm1(x3), sgn, x3 * cvv);
                x0 = __expf(x0); x1 = __expf(x1); x2 = __expf(x2); x3 = __expf(x3);
                x0 *= frcp(sum16(x0)); x1 *= frcp(sum16(x1));
                x2 *= frcp(sum16(x2)); x3 *= frcp(sum16(x3));
                kcsacc += x0 + x1 + x2 + x3;
            }
            unsigned short* dst = (ct < 2) ? kbuf : vbuf;
            int o = (ct & 1) * 16 + quad * 4;                 // o&7 in {0,4}, granule o>>3 in 0..3
            *(uint2*)(dst + n * 32 + (((o >> 3) ^ (n & 3)) << 3) + (o & 7)) =
                make_uint2(pk2(x0, x1), pk2(x2, x3));
        }

        // wave-local visibility: drain own ds_writes before cross-lane ds_reads
        asm volatile("s_waitcnt lgkmcnt(0)" ::: "memory");
        __builtin_amdgcn_sched_barrier(0);

        // kv partial over this rt's 32 slots: A = kbuf[n][slot], B = vbuf[n][slot]
        {
            int off = ((quad ^ (n & 3)) << 3);                // slot group quad*8, swizzled granule
            short8 Ak = *(const short8*)(kbuf + n * 32 + off);
            short8 Bv = *(const short8*)(vbuf + n * 32 + off);
            kvacc = __builtin_amdgcn_mfma_f32_16x16x32_bf16(Ak, Bv, kvacc, 0, 0, 0);
        }
        // next rt's ds_writes alias these ds_reads (WAR, same wave): DS pipe is in-order per wave.
    }

    // per-(block,wave) partials -> ws (no atomics here; k_red accumulates)
    kcsacc += __shfl_xor(kcsacc, 16); kcsacc += __shfl_xor(kcsacc, 32);
    float* part = ws + OFF_PART + ((long)blk * 4 + wave) * 272;
    #pragma unroll
    for (int r = 0; r < 4; ++r) part[(quad * 4 + r) * 16 + n] = kvacc[r];
    if (lane < 16) part[256 + n] = kcsacc;
}

// ---------------- reduce partials -> kv[32][16][16], kcs[32][16] (atomic, 8x parallel) ----------------
// 256 blocks: bh = blk>>3, record group g = blk&7 (32 records each). kv/kcs pre-zeroed in k_prep.
__global__ void k_red(float* __restrict__ ws) {
    int blk = blockIdx.x, t = threadIdx.x;
    if (t >= 272) return;
    int bh = blk >> 3, g = blk & 7;
    const float* part = ws + OFF_PART + (long)bh * 256 * 272 + (long)g * 32 * 272 + t;
    float s = 0.f;
    #pragma unroll 8
    for (int i = 0; i < 32; ++i) s += part[(long)i * 272];
    float* dst = (t < 256) ? (ws + OFF_KV + bh * 256 + t)
                           : (ws + OFF_KCS + bh * 16 + (t - 256));
    atomicAdd(dst, s);
}

// ---------------- K3 (R8): f = q + (q@kv)*Dinv, out = f@Wo^T + bo (all MFMA), 64-row blocks ----------------
// 64 out-rows/block, 1024 blocks = exactly 4/CU full residency. wave w: heads/out-chunks {2w, 2w+1}.
__global__ __launch_bounds__(256, 4) void k_out(const float* __restrict__ bo,
                                                float* __restrict__ ws,
                                                float* __restrict__ out) {
    __shared__ __align__(16) unsigned short tile[64 * 128];    // q then f (row-passed), 16KB
    const unsigned short* qws16 = (const unsigned short*)(ws + OFF_QWS);
    int t = threadIdx.x, blk = blockIdx.x;
    int wave = t >> 6, lane = t & 63, quad = lane >> 4, n = lane & 15;
    int b = blk >> 8;
    int sp0 = (blk & 255) * 64;

    // stage q tile: [row][col = h*16+j] bf16, swizzled (rr in 0..63)
    #pragma unroll
    for (int i = 0; i < 8; ++i) {
        int idx = i * 256 + t;
        int h = idx >> 8, rr = (idx >> 2) & 63, seg = idx & 3;
        uint2 u = *(const uint2*)(qws16 + ((long)(b * 8 + h) * 16384 + sp0 + rr) * 16 + seg * 4);
        unsigned short* p = tile + rr * 128 + (((h * 2 + (seg >> 1)) ^ (rr & 7)) << 3) + (seg & 1) * 4;
        *(uint2*)p = u;
    }

    // B-frags: kv/kcs (block-diag halves) for heads 2w, 2w+1; Wo frags for out cols
    short8 Bkv[2], Bden[2];
    #pragma unroll
    for (int ct = 0; ct < 2; ++ct) {
        int h = 2 * wave + ct;
        const float* kvp = ws + OFF_KV + (b * 8 + h) * 256;
        const float* ksp = ws + OFF_KCS + (b * 8 + h) * 16;
        short8 bk8 = {0, 0, 0, 0, 0, 0, 0, 0}, bd8 = {0, 0, 0, 0, 0, 0, 0, 0};
        bool act = (ct == 0) ? (quad < 2) : (quad >= 2);
        int kbase = (ct == 0) ? quad * 8 : (quad - 2) * 8;
        if (act) {
            #pragma unroll
            for (int jj = 0; jj < 8; ++jj) {
                bk8[jj] = (short)f2bf(kvp[(kbase + jj) * 16 + n]);
                bd8[jj] = (short)f2bf(ksp[kbase + jj]);
            }
        }
        Bkv[ct] = bk8; Bden[ct] = bd8;
    }
    const short8* fo = (const short8*)((const unsigned short*)(ws + OFF_FRG_O));
    short8 Bo[2][4];
    #pragma unroll
    for (int ct = 0; ct < 2; ++ct)
        #pragma unroll
        for (int km = 0; km < 4; ++km)
            Bo[ct][km] = fo[((2 * wave + ct) * 4 + km) * 64 + lane];
    __syncthreads();

    // two passes over row-halves (32 rows each): compute f, overwrite tile in place
    #pragma unroll
    for (int pass = 0; pass < 2; ++pass) {
        unsigned short fh[2][2][4];
        #pragma unroll
        for (int rtl = 0; rtl < 2; ++rtl) {
            int rt = pass * 2 + rtl;
            int row = rt * 16 + n;
            short8 Af = *(const short8*)(tile + row * 128 + (((wave * 4 + quad) ^ (n & 7)) << 3));
            float4v P0 = __builtin_amdgcn_mfma_f32_16x16x32_bf16(Af, Bkv[0], (float4v){0.f,0.f,0.f,0.f}, 0, 0, 0);
            float4v P1 = __builtin_amdgcn_mfma_f32_16x16x32_bf16(Af, Bkv[1], (float4v){0.f,0.f,0.f,0.f}, 0, 0, 0);
            float4v D0 = __builtin_amdgcn_mfma_f32_16x16x32_bf16(Af, Bden[0], (float4v){0.f,0.f,0.f,0.f}, 0, 0, 0);
            float4v D1 = __builtin_amdgcn_mfma_f32_16x16x32_bf16(Af, Bden[1], (float4v){0.f,0.f,0.f,0.f}, 0, 0, 0);
            #pragma unroll
            for (int ct = 0; ct < 2; ++ct) {
                int cg = 2 * wave + ct;
                float4v P = ct ? P1 : P0;
                float4v D = ct ? D1 : D0;
                #pragma unroll
                for (int i = 0; i < 4; ++i) {
                    int rw = rt * 16 + quad * 4 + i;
                    int col = cg * 16 + n;
                    float qv = bf2f(tile[rw * 128 + (((col >> 3) ^ (rw & 7)) << 3) + (col & 7)]);
                    float inv = frcp(fmaxf(D[i], 1e-8f));
                    fh[rtl][ct][i] = f2bf(fmaf(P[i], inv, qv));
                }
            }
        }
        __syncthreads();   // all q-reads of this row-half done everywhere
        #pragma unroll
        for (int rtl = 0; rtl < 2; ++rtl)
            #pragma unroll
            for (int ct = 0; ct < 2; ++ct) {
                int cg = 2 * wave + ct;
                #pragma unroll
                for (int i = 0; i < 4; ++i) {
                    int rw = (pass * 2 + rtl) * 16 + quad * 4 + i;
                    int col = cg * 16 + n;
                    tile[rw * 128 + (((col >> 3) ^ (rw & 7)) << 3) + (col & 7)] = fh[rtl][ct][i];
                }
            }
    }
    __syncthreads();

    // out = f @ Wo^T + bo, per-rt epilogue
    float bb0 = bo[(2 * wave) * 16 + n];
    float bb1 = bo[(2 * wave + 1) * 16 + n];
    #pragma unroll
    for (int rt = 0; rt < 4; ++rt) {
        float4v a0 = (float4v){0.f, 0.f, 0.f, 0.f};
        float4v a1 = (float4v){0.f, 0.f, 0.f, 0.f};
        int row = rt * 16 + n;
        #pragma unroll
        for (int km = 0; km < 4; ++km) {
            short8 Af = *(const short8*)(tile + row * 128 + (((km * 4 + quad) ^ (n & 7)) << 3));
            a0 = __builtin_amdgcn_mfma_f32_16x16x32_bf16(Af, Bo[0][km], a0, 0, 0, 0);
            a1 = __builtin_amdgcn_mfma_f32_16x16x32_bf16(Af, Bo[1][km], a1, 0, 0, 0);
        }
        #pragma unroll
        for (int ct = 0; ct < 2; ++ct) {
            int cg = 2 * wave + ct;
            float bb = ct ? bb1 : bb0;
            float4v a = ct ? a1 : a0;
            #pragma unroll
            for (int i = 0; i < 4; ++i) {
                float v = a[i] + bb;
                float pv = qperm1(v);
                if ((n & 1) == 0) {
                    long rg = (long)b * 16384 + sp0 + rt * 16 + quad * 4 + i;
                    *(float2*)(out + rg * 128 + cg * 16 + n) = make_float2(v, pv);
                }
            }
        }
    }
}

extern "C" void kernel_launch(void* const* d_in, const int* in_sizes, int n_in,
                              void* d_out, int out_size, void* d_ws, size_t ws_size,
                              hipStream_t stream) {
    (void)in_sizes; (void)n_in; (void)out_size; (void)ws_size;
    const float* edge = (const float*)d_in[1];
    const float* qd   = (const float*)d_in[2];
    const float* Wq   = (const float*)d_in[3];
    const float* bq   = (const float*)d_in[4];
    // d_in[0], d_in[5..8]: dead code in reference
    const float* Wk1  = (const float*)d_in[9];
    const float* bk1  = (const float*)d_in[10];
    const float* Wv1  = (const float*)d_in[11];
    const float* bv1  = (const float*)d_in[12];
    const float* Wo   = (const float*)d_in[13];
    const float* bo   = (const float*)d_in[14];
    float* ws  = (float*)d_ws;
    float* out = (float*)d_out;

    hipLaunchKernelGGL(k_prep, dim3(290),  dim3(256), 0, stream, Wq, Wk1, Wv1, Wo, ws);
    hipLaunchKernelGGL(k_main, dim3(2560), dim3(256), 0, stream, edge, bk1, bv1, qd, bq, ws);
    hipLaunchKernelGGL(k_red,  dim3(256),  dim3(320), 0, stream, ws);
    hipLaunchKernelGGL(k_out,  dim3(1024), dim3(256), 0, stream, bo, ws, out);
}